// Round 2
// baseline (256.372 us; speedup 1.0000x reference)
//
#include <hip/hip_runtime.h>

#define E_ 30
#define NB_ 12
#define F_ 1024
#define H_ 32
#define B_ 8192
#define L_ 128

typedef __attribute__((ext_vector_type(8))) _Float16 half8;
typedef __attribute__((ext_vector_type(4))) float f32x4;

#define GAS(p) ((const __attribute__((address_space(1))) void*)(p))
#define LAS(p) ((__attribute__((address_space(3))) void*)(p))

// ---------------------------------------------------------------------------
// Prepass: convert encodedFeatures (B,F) fp32 -> fp16, pre-tiled into MFMA
// A-fragment layout. Fragment = [16 m][32 k] = 1 KB contiguous; lane l of the
// consuming wave reads bytes [16l,16l+16) and expects A[m=l&15][k=(l>>4)*8+j],
// so the (m,k8) 8-element group goes to slot k8*16+m  (NOT m*4+k8 — that was
// the round-1 bug).
// ---------------------------------------------------------------------------
__global__ __launch_bounds__(256) void cvtA(const float* __restrict__ feat,
                                            _Float16* __restrict__ out) {
    int gid = blockIdx.x * 256 + threadIdx.x;      // 1,048,576 groups of 8
    int k8   = gid & 3;
    int m    = (gid >> 2) & 15;
    int frag = gid >> 6;                           // [bt(64)][kc(32)][mf(8)]
    int mf = frag & 7;
    int kc = (frag >> 3) & 31;
    int bt = frag >> 8;
    int b  = bt * 128 + mf * 16 + m;
    int f0 = kc * 32 + k8 * 8;
    const float4* src = (const float4*)(feat + (size_t)b * 1024 + f0);
    float4 v0 = src[0], v1 = src[1];
    half8 o;
    o[0] = (_Float16)v0.x; o[1] = (_Float16)v0.y;
    o[2] = (_Float16)v0.z; o[3] = (_Float16)v0.w;
    o[4] = (_Float16)v1.x; o[5] = (_Float16)v1.y;
    o[6] = (_Float16)v1.z; o[7] = (_Float16)v1.w;
    *(half8*)(out + ((size_t)frag * 64 + k8 * 16 + m) * 8) = o;
}

// ---------------------------------------------------------------------------
// Prepass: W1 (E,F,H) fp32 -> fp16 B-fragment layout:
// [e(30)][kc(32)][nf(2)] fragments; slot k8*16+n within each (same fix).
// ---------------------------------------------------------------------------
__global__ __launch_bounds__(256) void cvtW1(const float* __restrict__ W1,
                                             _Float16* __restrict__ out) {
    int gid = blockIdx.x * 256 + threadIdx.x;      // 122,880 groups of 8
    int k8   = gid & 3;
    int n    = (gid >> 2) & 15;
    int frag = gid >> 6;                           // [e(30)][kc(32)][nf(2)]
    int nf = frag & 1;
    int kc = (frag >> 1) & 31;
    int e  = frag >> 6;
    int h  = nf * 16 + n;
    int f0 = kc * 32 + k8 * 8;
    const float* src = W1 + ((size_t)e * 1024 + f0) * 32 + h;
    half8 o;
#pragma unroll
    for (int j = 0; j < 8; ++j) o[j] = (_Float16)src[j * 32];
    *(half8*)(out + ((size_t)frag * 64 + k8 * 16 + n) * 8) = o;
}

// ---------------------------------------------------------------------------
// Kernel 1: per (b-tile of 128, emotion) block.
//   GEMM1 (fp16 MFMA 16x16x32, BK=64, global_load_lds staging) -> selu ->
//   GEMM2 (H=32 -> NB=12, fp32) -> +allW +b2 -> signed L1 norm -> w to ws.
// w layout: (B, E, NB) fp32.
// ---------------------------------------------------------------------------
__global__ __launch_bounds__(256) void gemm_mlp(
    const _Float16* __restrict__ A16, const _Float16* __restrict__ W1T,
    const float* __restrict__ b1, const float* __restrict__ W2,
    const float* __restrict__ b2, const float* __restrict__ wts,
    float* __restrict__ wbuf) {
    __shared__ __align__(16) unsigned char smem[22400];
    float* h_sh = (float*)smem;                       // 128*33*4 = 16896 B (post-loop)
    unsigned char* Ash = smem;                        // 16 KB stage (K-loop)
    unsigned char* Bsh = smem + 16384;                //  4 KB stage (K-loop)
    float* w2s = (float*)(smem + 20480);              // 384 floats
    float* cb2 = (float*)(smem + 20480 + 1536);       // 12 floats (b2)
    float* ews = cb2 + 12;                            // 12 floats (exp(weights))

    const int tid = threadIdx.x;
    const int e  = blockIdx.x;    // 0..29  (x fastest -> e varies across
    const int bt = blockIdx.y;    // 0..63   concurrent blocks: A-tile L2 reuse)
    const int w  = tid >> 6, l = tid & 63;
    const int q  = l >> 4, lc = l & 15;

    for (int i = tid; i < 384; i += 256) w2s[i] = W2[e * 384 + i];
    if (tid < 12) {
        cb2[tid] = b2[e * 12 + tid];
        ews[tid] = __expf(wts[e * 12 + tid]);
    }

    const _Float16* Abase = A16 + (size_t)bt * 131072;
    const _Float16* Bbase = W1T + (size_t)e * 32768;

    f32x4 zero = {0.f, 0.f, 0.f, 0.f};
    f32x4 acc[2][2];
    acc[0][0] = zero; acc[0][1] = zero; acc[1][0] = zero; acc[1][1] = zero;

    for (int it = 0; it < 16; ++it) {
        const _Float16* Ait = Abase + it * 8192;  // 16 KB per iter (kc=2it,2it+1)
        const _Float16* Bit = Bbase + it * 2048;  //  4 KB per iter
#pragma unroll
        for (int i = 0; i < 4; ++i) {
            int s = w * 4 + i;
            __builtin_amdgcn_global_load_lds(GAS(Ait + s * 512 + l * 8),
                                             LAS(Ash + s * 1024), 16, 0, 0);
        }
        __builtin_amdgcn_global_load_lds(GAS(Bit + w * 512 + l * 8),
                                         LAS(Bsh + w * 1024), 16, 0, 0);
        __syncthreads();
#pragma unroll
        for (int kc2 = 0; kc2 < 2; ++kc2) {
            half8 a0  = *(half8*)(Ash + (kc2 * 8 + 2 * w + 0) * 1024 + l * 16);
            half8 a1  = *(half8*)(Ash + (kc2 * 8 + 2 * w + 1) * 1024 + l * 16);
            half8 bv0 = *(half8*)(Bsh + (kc2 * 2 + 0) * 1024 + l * 16);
            half8 bv1 = *(half8*)(Bsh + (kc2 * 2 + 1) * 1024 + l * 16);
            acc[0][0] = __builtin_amdgcn_mfma_f32_16x16x32_f16(a0, bv0, acc[0][0], 0, 0, 0);
            acc[0][1] = __builtin_amdgcn_mfma_f32_16x16x32_f16(a0, bv1, acc[0][1], 0, 0, 0);
            acc[1][0] = __builtin_amdgcn_mfma_f32_16x16x32_f16(a1, bv0, acc[1][0], 0, 0, 0);
            acc[1][1] = __builtin_amdgcn_mfma_f32_16x16x32_f16(a1, bv1, acc[1][1], 0, 0, 0);
        }
        __syncthreads();
    }

    // Epilogue: bias + selu -> h_sh[128][33] (pad 33 breaks bank conflicts)
    const float b1v0 = b1[e * 32 + lc];
    const float b1v1 = b1[e * 32 + 16 + lc];
    const float SC = 1.0507009873554805f, AL = 1.6732632423543772f;
#pragma unroll
    for (int mf = 0; mf < 2; ++mf)
#pragma unroll
        for (int nf = 0; nf < 2; ++nf)
#pragma unroll
            for (int r = 0; r < 4; ++r) {
                int m   = w * 32 + mf * 16 + q * 4 + r;   // C/D: row=(l>>4)*4+r
                int col = nf * 16 + lc;                   //      col=l&15
                float x = acc[mf][nf][r] + (nf ? b1v1 : b1v0);
                float hv = x > 0.f ? SC * x : SC * AL * (__expf(x) - 1.f);
                h_sh[m * 33 + col] = hv;
            }
    __syncthreads();

    // GEMM2 + normalize: 2 threads per row, 6 outputs each
    const int m2 = tid >> 1, sub = tid & 1;
    float u[6] = {0.f, 0.f, 0.f, 0.f, 0.f, 0.f};
    const float* hrow = h_sh + m2 * 33;
#pragma unroll 8
    for (int h = 0; h < 32; ++h) {
        float hv = hrow[h];
        const float* wr = w2s + h * 12 + sub * 6;
#pragma unroll
        for (int j = 0; j < 6; ++j) u[j] += hv * wr[j];
    }
    float sew = 0.f;
#pragma unroll
    for (int i = 0; i < 12; ++i) sew += ews[i];
    sew = fmaxf(sew, 1e-12f);
    float sabs = 0.f;
#pragma unroll
    for (int j = 0; j < 6; ++j) {
        u[j] += cb2[sub * 6 + j] + ews[sub * 6 + j] / sew;
        sabs += fabsf(u[j]);
    }
    sabs += __shfl_xor(sabs, 1);
    float inv = 1.f / fmaxf(sabs, 1e-12f);
    int b = bt * 128 + m2;
    float* dst = wbuf + (size_t)b * 360 + e * 12 + sub * 6;
#pragma unroll
    for (int j = 0; j < 6; ++j) dst[j] = u[j] * inv;
}

// ---------------------------------------------------------------------------
// Kernel 2: mixed = w . dist, softmax over L. 8 rows/block; dist register-
// cached (12 x float4 per thread) across all 30 emotions -> dist read once.
// ---------------------------------------------------------------------------
__global__ __launch_bounds__(256) void mix_softmax(
    const float* __restrict__ dist, const float* __restrict__ wbuf,
    float* __restrict__ out) {
    __shared__ float wsm[8 * 360];
    const int tid = threadIdx.x;
    const int b0 = blockIdx.x * 8;
    for (int i = tid; i < 2880; i += 256) wsm[i] = wbuf[(size_t)b0 * 360 + i];
    __syncthreads();
    const int m = tid >> 5, l4 = tid & 31;
    const int b = b0 + m;
    const float* dbase = dist + (size_t)b * 1536 + l4 * 4;
    f32x4 d[12];
#pragma unroll
    for (int n = 0; n < 12; ++n) d[n] = *(const f32x4*)(dbase + n * 128);
    const float* wrow = wsm + m * 360;
    for (int e = 0; e < 30; ++e) {
        const float* wr = wrow + e * 12;
        f32x4 a = {0.f, 0.f, 0.f, 0.f};
#pragma unroll
        for (int n = 0; n < 12; ++n) a += wr[n] * d[n];
        float mx = fmaxf(fmaxf(a[0], a[1]), fmaxf(a[2], a[3]));
#pragma unroll
        for (int s = 16; s >= 1; s >>= 1) mx = fmaxf(mx, __shfl_xor(mx, s));
        f32x4 ex;
        ex[0] = __expf(a[0] - mx); ex[1] = __expf(a[1] - mx);
        ex[2] = __expf(a[2] - mx); ex[3] = __expf(a[3] - mx);
        float sm = ex[0] + ex[1] + ex[2] + ex[3];
#pragma unroll
        for (int s = 16; s >= 1; s >>= 1) sm += __shfl_xor(sm, s);
        f32x4 o = ex * (1.f / sm);
        *(f32x4*)(out + ((size_t)e * 8192 + b) * 128 + l4 * 4) = o;
    }
}

// ---------------------------------------------------------------------------
extern "C" void kernel_launch(void* const* d_in, const int* in_sizes, int n_in,
                              void* d_out, int out_size, void* d_ws, size_t ws_size,
                              hipStream_t stream) {
    const float* dist = (const float*)d_in[0];   // (B, NB, L)
    const float* feat = (const float*)d_in[1];   // (B, F)
    const float* wts  = (const float*)d_in[2];   // (E,1,NB,1)
    const float* W1   = (const float*)d_in[3];   // (E, F, H)
    const float* b1   = (const float*)d_in[4];   // (E, H)
    const float* W2   = (const float*)d_in[5];   // (E, H, NB)
    const float* b2   = (const float*)d_in[6];   // (E, NB)
    float* out = (float*)d_out;                  // (E, B, L)

    _Float16* A16 = (_Float16*)d_ws;                            // 16,777,216 B
    _Float16* W1T = (_Float16*)((char*)d_ws + 16777216);        //  1,966,080 B
    float*   wbuf = (float*)((char*)d_ws + 16777216 + 1966080); // 11,796,480 B

    cvtA<<<4096, 256, 0, stream>>>(feat, A16);
    cvtW1<<<480, 256, 0, stream>>>(W1, W1T);
    dim3 g1(30, 64);
    gemm_mlp<<<g1, 256, 0, stream>>>(A16, W1T, b1, W2, b2, wts, wbuf);
    mix_softmax<<<1024, 256, 0, stream>>>(dist, wbuf, out);
}

// Round 3
// 253.371 us; speedup vs baseline: 1.0118x; 1.0118x over previous
//
#include <hip/hip_runtime.h>

typedef __attribute__((ext_vector_type(8))) _Float16 half8;
typedef __attribute__((ext_vector_type(4))) float f32x4;

#define GAS(p) ((const __attribute__((address_space(1))) void*)(p))
#define LAS(p) ((__attribute__((address_space(3))) void*)(p))

// ---------------------------------------------------------------------------
// Merged prepass. Blocks [0,4096): feat (B,F) fp32 -> fp16 A-fragments.
// Blocks [4096,4576): W1 (E,F,H) fp32 -> fp16 B-fragments.
// Fragment = contiguous 1 KB [16 rows][32 k]; 8-elem group (row,k8) at slot
// k8*16+row so consuming lane l reads bytes [16l,16l+16) = A[m=l&15][k=(l>>4)*8+j].
// ---------------------------------------------------------------------------
__global__ __launch_bounds__(256) void cvt_pre(const float* __restrict__ feat,
                                               const float* __restrict__ W1,
                                               _Float16* __restrict__ A16,
                                               _Float16* __restrict__ W1T) {
    if (blockIdx.x < 4096) {
        int gid = blockIdx.x * 256 + threadIdx.x;      // 1,048,576 groups of 8
        int k8   = gid & 3;
        int m    = (gid >> 2) & 15;
        int frag = gid >> 6;                           // [bt(64)][kc(32)][mf(8)]
        int mf = frag & 7;
        int kc = (frag >> 3) & 31;
        int bt = frag >> 8;
        int b  = bt * 128 + mf * 16 + m;
        int f0 = kc * 32 + k8 * 8;
        const float4* src = (const float4*)(feat + (size_t)b * 1024 + f0);
        float4 v0 = src[0], v1 = src[1];
        half8 o;
        o[0] = (_Float16)v0.x; o[1] = (_Float16)v0.y;
        o[2] = (_Float16)v0.z; o[3] = (_Float16)v0.w;
        o[4] = (_Float16)v1.x; o[5] = (_Float16)v1.y;
        o[6] = (_Float16)v1.z; o[7] = (_Float16)v1.w;
        *(half8*)(A16 + ((size_t)frag * 64 + k8 * 16 + m) * 8) = o;
    } else {
        int gid = (blockIdx.x - 4096) * 256 + threadIdx.x;  // 122,880 groups
        int k8   = gid & 3;
        int n    = (gid >> 2) & 15;
        int frag = gid >> 6;                           // [e(30)][kc(32)][nf(2)]
        int nf = frag & 1;
        int kc = (frag >> 1) & 31;
        int e  = frag >> 6;
        int h  = nf * 16 + n;
        int f0 = kc * 32 + k8 * 8;
        const float* src = W1 + ((size_t)e * 1024 + f0) * 32 + h;
        half8 o;
#pragma unroll
        for (int j = 0; j < 8; ++j) o[j] = (_Float16)src[j * 32];
        *(half8*)(W1T + ((size_t)frag * 64 + k8 * 16 + n) * 8) = o;
    }
}

// ---------------------------------------------------------------------------
// Kernel 1: block = (128 b-rows, 2 emotions). GEMM1 fp16 MFMA (BK=64,
// global_load_lds) -> selu -> GEMM2 (fp32) -> +allW+b2 -> signed L1 norm.
// Per kc-step: 6 ds_read_b128 : 8 MFMA. wbuf layout (E, B, NB) -> coalesced
// epilogue stores.
// ---------------------------------------------------------------------------
__global__ __launch_bounds__(256) void gemm_mlp(
    const _Float16* __restrict__ A16, const _Float16* __restrict__ W1T,
    const float* __restrict__ b1, const float* __restrict__ W2,
    const float* __restrict__ b2, const float* __restrict__ wts,
    float* __restrict__ wbuf) {
    __shared__ __align__(16) unsigned char smem[28672];
    unsigned char* Ash = smem;                        // 16 KB stage (K-loop)
    unsigned char* Bsh = smem + 16384;                //  8 KB stage (K-loop)
    float* w2s = (float*)(smem + 24576);              // 768 floats (2 e)
    float* cb2 = (float*)(smem + 27648);              // 24 floats
    float* ews = cb2 + 24;                            // 24 floats
    float* h_sh = (float*)smem;                       // 128*33*4 B (post-loop)

    const int tid = threadIdx.x;
    const int e0 = blockIdx.x * 2;   // emotion pair 0..14
    const int bt = blockIdx.y;       // 0..63
    const int w  = tid >> 6, l = tid & 63;
    const int q  = l >> 4, lc = l & 15;

    for (int i = tid; i < 768; i += 256) w2s[i] = W2[e0 * 384 + i];
    if (tid < 24) {
        cb2[tid] = b2[e0 * 12 + tid];
        ews[tid] = __expf(wts[e0 * 12 + tid]);
    }

    const _Float16* Abase = A16 + (size_t)bt * 131072;
    const _Float16* Bbase = W1T + (size_t)e0 * 32768;

    f32x4 zero = {0.f, 0.f, 0.f, 0.f};
    f32x4 acc[2][4];                 // [mf][(be<<1)|nf]
#pragma unroll
    for (int i = 0; i < 2; ++i)
#pragma unroll
        for (int j = 0; j < 4; ++j) acc[i][j] = zero;

    for (int it = 0; it < 16; ++it) {
        const _Float16* Ait = Abase + it * 8192;   // 16 KB (kc = 2it, 2it+1)
#pragma unroll
        for (int i = 0; i < 4; ++i) {
            int s = w * 4 + i;
            __builtin_amdgcn_global_load_lds(GAS(Ait + s * 512 + l * 8),
                                             LAS(Ash + s * 1024), 16, 0, 0);
        }
#pragma unroll
        for (int j = 0; j < 2; ++j) {
            int f  = w * 2 + j;                    // 8 B-frags: [be(2)][kc2(2)][nf(2)]
            int be = f >> 2, kn = f & 3;
            __builtin_amdgcn_global_load_lds(
                GAS(Bbase + be * 32768 + it * 2048 + kn * 512 + l * 8),
                LAS(Bsh + f * 1024), 16, 0, 0);
        }
        __syncthreads();
#pragma unroll
        for (int kc2 = 0; kc2 < 2; ++kc2) {
            half8 a0  = *(half8*)(Ash + (kc2 * 8 + 2 * w + 0) * 1024 + l * 16);
            half8 a1  = *(half8*)(Ash + (kc2 * 8 + 2 * w + 1) * 1024 + l * 16);
            half8 b00 = *(half8*)(Bsh + (0 + kc2 * 2 + 0) * 1024 + l * 16);
            half8 b01 = *(half8*)(Bsh + (0 + kc2 * 2 + 1) * 1024 + l * 16);
            half8 b10 = *(half8*)(Bsh + (4 + kc2 * 2 + 0) * 1024 + l * 16);
            half8 b11 = *(half8*)(Bsh + (4 + kc2 * 2 + 1) * 1024 + l * 16);
            acc[0][0] = __builtin_amdgcn_mfma_f32_16x16x32_f16(a0, b00, acc[0][0], 0, 0, 0);
            acc[0][1] = __builtin_amdgcn_mfma_f32_16x16x32_f16(a0, b01, acc[0][1], 0, 0, 0);
            acc[0][2] = __builtin_amdgcn_mfma_f32_16x16x32_f16(a0, b10, acc[0][2], 0, 0, 0);
            acc[0][3] = __builtin_amdgcn_mfma_f32_16x16x32_f16(a0, b11, acc[0][3], 0, 0, 0);
            acc[1][0] = __builtin_amdgcn_mfma_f32_16x16x32_f16(a1, b00, acc[1][0], 0, 0, 0);
            acc[1][1] = __builtin_amdgcn_mfma_f32_16x16x32_f16(a1, b01, acc[1][1], 0, 0, 0);
            acc[1][2] = __builtin_amdgcn_mfma_f32_16x16x32_f16(a1, b10, acc[1][2], 0, 0, 0);
            acc[1][3] = __builtin_amdgcn_mfma_f32_16x16x32_f16(a1, b11, acc[1][3], 0, 0, 0);
        }
        __syncthreads();
    }

    const float SC = 1.0507009873554805f, AL = 1.6732632423543772f;
    const int m2 = tid >> 1, sub = tid & 1;

#pragma unroll
    for (int eo = 0; eo < 2; ++eo) {
        // bias + selu -> h_sh[128][33]
        const float b1a = b1[(e0 + eo) * 32 + lc];
        const float b1b = b1[(e0 + eo) * 32 + 16 + lc];
#pragma unroll
        for (int mf = 0; mf < 2; ++mf)
#pragma unroll
            for (int nf = 0; nf < 2; ++nf)
#pragma unroll
                for (int r = 0; r < 4; ++r) {
                    int m   = w * 32 + mf * 16 + q * 4 + r;  // row=(l>>4)*4+r
                    int col = nf * 16 + lc;                  // col=l&15
                    float x = acc[mf][eo * 2 + nf][r] + (nf ? b1b : b1a);
                    float hv = x > 0.f ? SC * x : SC * AL * (__expf(x) - 1.f);
                    h_sh[m * 33 + col] = hv;
                }
        __syncthreads();

        // GEMM2 + normalize: 2 threads per row, 6 outputs each
        float u[6] = {0.f, 0.f, 0.f, 0.f, 0.f, 0.f};
        const float* hrow = h_sh + m2 * 33;
        const float* wbase = w2s + eo * 384 + sub * 6;
#pragma unroll 8
        for (int h = 0; h < 32; ++h) {
            float hv = hrow[h];
            const float* wr = wbase + h * 12;
#pragma unroll
            for (int j = 0; j < 6; ++j) u[j] += hv * wr[j];
        }
        float sew = 0.f;
#pragma unroll
        for (int i = 0; i < 12; ++i) sew += ews[eo * 12 + i];
        sew = fmaxf(sew, 1e-12f);
        float sabs = 0.f;
#pragma unroll
        for (int j = 0; j < 6; ++j) {
            u[j] += cb2[eo * 12 + sub * 6 + j] + ews[eo * 12 + sub * 6 + j] / sew;
            sabs += fabsf(u[j]);
        }
        sabs += __shfl_xor(sabs, 1);
        float inv = 1.f / fmaxf(sabs, 1e-12f);
        int b = bt * 128 + m2;
        float* dst = wbuf + (size_t)(e0 + eo) * 98304 + b * 12 + sub * 6;
#pragma unroll
        for (int j = 0; j < 6; ++j) dst[j] = u[j] * inv;
        __syncthreads();   // protect h_sh before next eo overwrites
    }
}

// ---------------------------------------------------------------------------
// Kernel 2: mixed = w . dist, softmax over L. 8 rows/block; dist register-
// cached. No max pass: sum|w|=1 and dist in [0,1) => |mixed| < 1, exp safe.
// ---------------------------------------------------------------------------
__global__ __launch_bounds__(256) void mix_softmax(
    const float* __restrict__ dist, const float* __restrict__ wbuf,
    float* __restrict__ out) {
    __shared__ float wsm[8 * 360];                    // [m][e][n]
    const int tid = threadIdx.x;
    const int b0 = blockIdx.x * 8;
    for (int i = tid; i < 2880; i += 256) {
        int e = i / 96, r = i - e * 96;               // r = m*12+n
        wsm[(r / 12) * 360 + e * 12 + (r % 12)] = wbuf[(size_t)e * 98304 + b0 * 12 + r];
    }
    __syncthreads();
    const int m = tid >> 5, l4 = tid & 31;
    const int b = b0 + m;
    const float* dbase = dist + (size_t)b * 1536 + l4 * 4;
    f32x4 d[12];
#pragma unroll
    for (int n = 0; n < 12; ++n) d[n] = *(const f32x4*)(dbase + n * 128);
    const float* wrow = wsm + m * 360;
    for (int e = 0; e < 30; ++e) {
        const float* wr = wrow + e * 12;
        f32x4 a = {0.f, 0.f, 0.f, 0.f};
#pragma unroll
        for (int n = 0; n < 12; ++n) a += wr[n] * d[n];
        f32x4 ex;
        ex[0] = __expf(a[0]); ex[1] = __expf(a[1]);
        ex[2] = __expf(a[2]); ex[3] = __expf(a[3]);
        float sm = ex[0] + ex[1] + ex[2] + ex[3];
#pragma unroll
        for (int s = 16; s >= 1; s >>= 1) sm += __shfl_xor(sm, s);
        f32x4 o = ex * (1.f / sm);
        *(f32x4*)(out + ((size_t)e * 8192 + b) * 128 + l4 * 4) = o;
    }
}

// ---------------------------------------------------------------------------
extern "C" void kernel_launch(void* const* d_in, const int* in_sizes, int n_in,
                              void* d_out, int out_size, void* d_ws, size_t ws_size,
                              hipStream_t stream) {
    const float* dist = (const float*)d_in[0];   // (B, NB, L)
    const float* feat = (const float*)d_in[1];   // (B, F)
    const float* wts  = (const float*)d_in[2];   // (E,1,NB,1)
    const float* W1   = (const float*)d_in[3];   // (E, F, H)
    const float* b1   = (const float*)d_in[4];   // (E, H)
    const float* W2   = (const float*)d_in[5];   // (E, H, NB)
    const float* b2   = (const float*)d_in[6];   // (E, NB)
    float* out = (float*)d_out;                  // (E, B, L)

    _Float16* A16 = (_Float16*)d_ws;                            // 16,777,216 B
    _Float16* W1T = (_Float16*)((char*)d_ws + 16777216);        //  1,966,080 B
    float*   wbuf = (float*)((char*)d_ws + 16777216 + 1966080); // 11,796,480 B (E,B,NB)

    cvt_pre<<<4576, 256, 0, stream>>>(feat, W1, A16, W1T);
    dim3 g1(15, 64);
    gemm_mlp<<<g1, 256, 0, stream>>>(A16, W1T, b1, W2, b2, wts, wbuf);
    mix_softmax<<<1024, 256, 0, stream>>>(dist, wbuf, out);
}